// Round 6
// baseline (2275.261 us; speedup 1.0000x reference)
//
#include <hip/hip_runtime.h>

#define N_NODES 10000
#define E_EDGES 32768
#define NEB (E_EDGES/64)   // 512 edge-blocks

typedef short bf16x8v __attribute__((ext_vector_type(8)));
typedef short bf16x4v __attribute__((ext_vector_type(4)));
typedef float f32x4   __attribute__((ext_vector_type(4)));

__device__ __forceinline__ float bf2f(ushort u){
    union{ uint i; float f; } v; v.i = ((uint)u) << 16; return v.f;
}
__device__ __forceinline__ ushort f2bf(float f){
    union{ float f; uint i; } v; v.f = f;
    uint u = v.i;
    return (ushort)((u + 0x7fffu + ((u >> 16) & 1u)) >> 16);
}
__device__ __forceinline__ float ldf(float v){ return v; }
__device__ __forceinline__ float ldf(ushort v){ return bf2f(v); }

// async 16B global -> LDS (wave-uniform LDS base + lane*16)
__device__ __forceinline__ void async_copy16(const void* g, void* l){
    __builtin_amdgcn_global_load_lds(
        (const __attribute__((address_space(1))) void*)g,
        (__attribute__((address_space(3))) void*)l, 16, 0, 0);
}

// ---------------------------------------------------------------------------
// edge_index normalization: detect int32 vs int64 layout, clamp, write int32.
// ---------------------------------------------------------------------------
__global__ void idx_detect(const int* __restrict__ w, int* __restrict__ flag){
    __shared__ int sh[256];
    int t = threadIdx.x;
    int o = 0;
    for (int i = 2*t + 1; i < 2*E_EDGES; i += 512) o |= w[i];
    sh[t] = o; __syncthreads();
    for (int s = 128; s; s >>= 1){ if (t < s) sh[t] |= sh[t+s]; __syncthreads(); }
    if (t == 0) *flag = sh[0];
}

__global__ void idx_norm(const int* __restrict__ w, const int* __restrict__ flag,
                         int* __restrict__ srcN, int* __restrict__ dstN){
    int e = blockIdx.x*256 + threadIdx.x;
    if (e >= E_EDGES) return;
    int s, d;
    if (*flag){ s = w[e];     d = w[E_EDGES + e]; }          // int32 layout
    else      { s = w[2*e];   d = w[2*E_EDGES + 2*e]; }      // int64 layout (low words)
    s = min(max(s, 0), N_NODES-1);
    d = min(max(d, 0), N_NODES-1);
    srcN[e] = s; dstN[e] = d;
}

// ---------------------------------------------------------------------------
// Fused per-edge-MLP GEMM + einsum + scatter-add, i-major K-chained.
// Block (eb, kz): 64 edges x K-range [kz*CH*64, +CH*64). All CH A-chunks staged
// in LDS up-front; inner loop chains acc over kc via MFMA C operand, so the
// per-edge h-scale epilogue runs once per i-pair (amortized over CH*16 MFMA).
// LDS 8-oct XOR swizzle (conflict-free), swizzle folded into DMA global addr.
// ---------------------------------------------------------------------------
template<int K, int NI, int KS, typename TH>
__global__ __launch_bounds__(256, 2)
void gemm_msg(const float* __restrict__ ea4,
              const int* __restrict__ srcI, const int* __restrict__ dstI,
              const float* __restrict__ w1, const float* __restrict__ b1,
              const ushort* __restrict__ Bt, const float* __restrict__ b2,
              const TH* __restrict__ hsrc,
              float* __restrict__ nodesum)
{
    constexpr int CH = K / 64 / KS;   // K-chunks per block (resident in As)
    constexpr int IP = NI / 2;        // i-pair passes (Ntile = 128)

    __shared__ __align__(16) ushort As[CH][64 * 64];    // A chunks, swizzled
    __shared__ __align__(16) ushort Bs[2][128 * 64];    // B tile dbuf, swizzled
    __shared__ __align__(16) ushort h_s[NI][68];        // h-scale transposed [i][row]
    __shared__ float ea_s[256];
    __shared__ int src_s[64];
    __shared__ int dst_s[64];

    const int bid  = blockIdx.x;
    const int eb   = bid % NEB;
    const int kz   = bid / NEB;
    const int t    = threadIdx.x;
    const int e0   = eb * 64;
    const int lane = t & 63;
    const int wv   = t >> 6;
    const int ng   = wv & 1;
    const int kg   = wv >> 1;
    const int q    = lane >> 4;
    const int ln   = lane & 15;

    if (t < 64){ src_s[t] = srcI[e0 + t]; dst_s[t] = dstI[e0 + t]; }
    ea_s[t] = ea4[e0 * 4 + t];
    __syncthreads();

    // stage h_s[i][row]
    if (NI == 64){
        int r = t >> 2, ig = t & 3;
        const ushort* hp = (const ushort*)hsrc + (size_t)src_s[r] * 64 + ig * 16;
        uint4 v0 = *(const uint4*)(hp);
        uint4 v1 = *(const uint4*)(hp + 8);
        const ushort* p0 = (const ushort*)&v0;
        const ushort* p1 = (const ushort*)&v1;
        #pragma unroll
        for (int ii = 0; ii < 8; ii++) h_s[ig*16 + ii    ][r] = p0[ii];
        #pragma unroll
        for (int ii = 0; ii < 8; ii++) h_s[ig*16 + 8 + ii][r] = p1[ii];
    } else {
        if (t < 64){
            const TH* hp = hsrc + (size_t)src_s[t] * NI;
            #pragma unroll
            for (int ii = 0; ii < NI; ii++) h_s[ii][t] = f2bf(ldf(hp[ii]));
        }
    }

    // async DMA of one 128x64 B tile into Bs[buf]; swizzle folded into global addr
    const int rl = lane >> 3, oc = lane & 7;
    const int ocs = oc ^ (rl & 7);
    auto asyncB = [&](int ip, int kc, int buf){
        int kcg = kz * CH + kc;
        #pragma unroll
        for (int j = 0; j < 4; j++){
            const ushort* gp = Bt + (size_t)(ip * 128 + wv * 32 + j * 8 + rl) * K
                                  + kcg * 64 + ocs * 8;
            async_copy16(gp, &Bs[buf][(wv * 32 + j * 8) * 64]);
        }
    };

    asyncB(0, 0, 0);

    // stage all CH A-chunks (on-the-fly edge MLP layer 1)
    #pragma unroll 1
    for (int kc = 0; kc < CH; kc++){
        int kcg = kz * CH + kc;
        #pragma unroll
        for (int s2 = 0; s2 < 2; s2++){
            int a = t + s2 * 256;
            int r = a >> 3, oct = a & 7;
            int k = kcg * 64 + oct * 8;
            float acc8[8];
            float4 b0 = *(const float4*)(b1 + k);
            float4 b4 = *(const float4*)(b1 + k + 4);
            acc8[0]=b0.x; acc8[1]=b0.y; acc8[2]=b0.z; acc8[3]=b0.w;
            acc8[4]=b4.x; acc8[5]=b4.y; acc8[6]=b4.z; acc8[7]=b4.w;
            #pragma unroll
            for (int a4 = 0; a4 < 4; a4++){
                float4 w0 = *(const float4*)(w1 + (size_t)a4 * K + k);
                float4 w4 = *(const float4*)(w1 + (size_t)a4 * K + k + 4);
                float m = ea_s[r * 4 + a4];
                acc8[0] += m * w0.x; acc8[1] += m * w0.y;
                acc8[2] += m * w0.z; acc8[3] += m * w0.w;
                acc8[4] += m * w4.x; acc8[5] += m * w4.y;
                acc8[6] += m * w4.z; acc8[7] += m * w4.w;
            }
            uint4 ov;
            ushort* po = (ushort*)&ov;
            #pragma unroll
            for (int j = 0; j < 8; j++) po[j] = f2bf(fmaxf(acc8[j], 0.f));
            *(uint4*)&As[kc][r * 64 + ((oct ^ (r & 7)) * 8)] = ov;
        }
    }
    __syncthreads();

    f32x4 msg[4][4];
    #pragma unroll
    for (int a = 0; a < 4; a++)
        #pragma unroll
        for (int b = 0; b < 4; b++){ msg[a][b][0]=0.f; msg[a][b][1]=0.f; msg[a][b][2]=0.f; msg[a][b][3]=0.f; }

    const f32x4 fzero = {0.f, 0.f, 0.f, 0.f};
    const int jx = ((kg * 4 + q) ^ (ln & 7)) * 8;   // swizzled k-oct offset (row&7 == ln&7 everywhere)
    int g = 0;
    #pragma unroll 1
    for (int ip = 0; ip < IP; ip++){
        f32x4 acc[4][4];
        #pragma unroll
        for (int kc = 0; kc < CH; kc++, g++){
            int buf = g & 1;
            if (kc + 1 < CH)        asyncB(ip, kc + 1, buf ^ 1);
            else if (ip + 1 < IP)   asyncB(ip + 1, 0, buf ^ 1);

            bf16x8v af[4], bfr[4];
            #pragma unroll
            for (int ms = 0; ms < 4; ms++)
                af[ms] = *(const bf16x8v*)&As[kc][(ms * 16 + ln) * 64 + jx];
            #pragma unroll
            for (int ns = 0; ns < 4; ns++)
                bfr[ns] = *(const bf16x8v*)&Bs[buf][(ng * 64 + ns * 16 + ln) * 64 + jx];

            #pragma unroll
            for (int ms = 0; ms < 4; ms++)
                #pragma unroll
                for (int ns = 0; ns < 4; ns++)
                    acc[ms][ns] = __builtin_amdgcn_mfma_f32_16x16x32_bf16(
                        af[ms], bfr[ns], (kc == 0) ? fzero : acc[ms][ns], 0, 0, 0);
            __syncthreads();
        }
        // h-scale epilogue, once per i-pair (amortized over CH*16 MFMA)
        int i2 = ip * 2 + ng;
        #pragma unroll
        for (int ms = 0; ms < 4; ms++){
            bf16x4v hb = *(const bf16x4v*)&h_s[i2][ms * 16 + q * 4];
            float hf[4];
            #pragma unroll
            for (int j = 0; j < 4; j++) hf[j] = bf2f((ushort)hb[j]);
            #pragma unroll
            for (int ns = 0; ns < 4; ns++)
                #pragma unroll
                for (int j = 0; j < 4; j++)
                    msg[ms][ns][j] += hf[j] * acc[ms][ns][j];
        }
    }

    // reduce the 4 waves' msg partials in LDS (reuse Bs), add b2 term (kz==0), scatter
    float* mr = (float*)&Bs[0][0];   // [64][65] f32
    #pragma unroll 1
    for (int r4 = 0; r4 < 4; r4++){
        if (wv == r4){
            #pragma unroll
            for (int ms = 0; ms < 4; ms++)
                #pragma unroll
                for (int ns = 0; ns < 4; ns++)
                    #pragma unroll
                    for (int j = 0; j < 4; j++){
                        int row = ms * 16 + q * 4 + j, col = ns * 16 + ln;
                        if (r4 == 0) mr[row * 65 + col]  = msg[ms][ns][j];
                        else         mr[row * 65 + col] += msg[ms][ns][j];
                    }
        }
        __syncthreads();
    }
    #pragma unroll 1
    for (int s2 = 0; s2 < 16; s2++){
        int a = t + s2 * 256;
        int row = a >> 6, o = a & 63;
        float v = mr[row * 65 + o];
        if (kz == 0){
            #pragma unroll 1
            for (int ii = 0; ii < NI; ii++)
                v += bf2f(h_s[ii][row]) * b2[ii * 64 + o];
        }
        atomicAdd(nodesum + (size_t)dst_s[row] * 64 + o, v);
    }
}

// ---------------------------------------------------------------------------
__global__ void transpose_f2b(const float* __restrict__ in, ushort* __restrict__ out, int D){
    __shared__ float tl[32][33];
    int bx = blockIdx.x, by = blockIdx.y;
    int tx = threadIdx.x, ty = threadIdx.y;
    #pragma unroll
    for (int r = 0; r < 4; r++)
        tl[ty + 8*r][tx] = in[(size_t)(by*32 + ty + 8*r) * D + bx*32 + tx];
    __syncthreads();
    #pragma unroll
    for (int r = 0; r < 4; r++)
        out[(size_t)(bx*32 + ty + 8*r) * D + by*32 + tx] = f2bf(tl[tx][ty + 8*r]);
}

__global__ void count_k(const int* __restrict__ dstI, float* __restrict__ cnt){
    int e = blockIdx.x * 256 + threadIdx.x;
    if (e < E_EDGES) atomicAdd(cnt + dstI[e], 1.f);
}

template<int NIn, typename TI>
__global__ void node_k(const float* __restrict__ ns_, const float* __restrict__ cnt,
                       const TI* __restrict__ xin, const float* __restrict__ root,
                       const float* __restrict__ bias,
                       ushort* __restrict__ hb, float* __restrict__ hf, int Nn)
{
    int idx = blockIdx.x * 256 + threadIdx.x;
    if (idx >= Nn * 64) return;
    int n = idx >> 6, o = idx & 63;
    float c = cnt[n];
    float inv = c > 1.f ? 1.f / c : 1.f;
    float s = ns_[idx] * inv + bias[o];
    #pragma unroll
    for (int i = 0; i < NIn; i++)
        s += ldf(xin[(size_t)n * NIn + i]) * root[i * 64 + o];
    s = fmaxf(s, 0.f);
    if (hb) hb[idx] = f2bf(s);
    else    hf[idx] = s;
}

// outputs FLOAT32: [E] prob | [E,3] types | [E] src | [E] dst
__global__ void edge_out_k(const float* __restrict__ h2, const int* __restrict__ srcI,
                           const int* __restrict__ dstI, const float* __restrict__ ea,
                           const float* __restrict__ fcw, const float* __restrict__ fcb,
                           float* __restrict__ out)
{
    __shared__ float fw[396];
    __shared__ float fb[3];
    int t = threadIdx.x;
    for (int i = t; i < 396; i += 256) fw[i] = fcw[i];
    if (t < 3) fb[t] = fcb[t];
    __syncthreads();
    int e = blockIdx.x * 256 + t;
    int s = srcI[e], d = dstI[e];
    const float* hs = h2 + (size_t)s * 64;
    const float* hd = h2 + (size_t)d * 64;
    float dot = 0.f, l0 = fb[0], l1 = fb[1], l2 = fb[2];
    #pragma unroll 8
    for (int c = 0; c < 64; c++){
        float a = hs[c], b = hd[c];
        dot += a * b;
        l0 += a * fw[c*3+0] + b * fw[(64+c)*3+0];
        l1 += a * fw[c*3+1] + b * fw[(64+c)*3+1];
        l2 += a * fw[c*3+2] + b * fw[(64+c)*3+2];
    }
    #pragma unroll
    for (int a4 = 0; a4 < 4; a4++){
        float v = ea[e*4 + a4];
        l0 += v * fw[(128+a4)*3+0];
        l1 += v * fw[(128+a4)*3+1];
        l2 += v * fw[(128+a4)*3+2];
    }
    float prob = 1.f / (1.f + __expf(-dot));
    float m  = fmaxf(l0, fmaxf(l1, l2));
    float x0 = __expf(l0 - m), x1 = __expf(l1 - m), x2 = __expf(l2 - m);
    float inv = 1.f / (x0 + x1 + x2);
    out[e]                  = prob;
    out[E_EDGES + 3*e + 0]  = x0 * inv;
    out[E_EDGES + 3*e + 1]  = x1 * inv;
    out[E_EDGES + 3*e + 2]  = x2 * inv;
    out[4*E_EDGES + e]      = (float)s;
    out[5*E_EDGES + e]      = (float)d;
}

// ---------------------------------------------------------------------------
extern "C" void kernel_launch(void* const* d_in, const int* in_sizes, int n_in,
                              void* d_out, int out_size, void* d_ws, size_t ws_size,
                              hipStream_t stream)
{
    const float* x     = (const float*)d_in[0];
    const int*   ei    = (const int*)  d_in[1];
    const float* ea    = (const float*)d_in[2];
    const float* e1w1  = (const float*)d_in[3];
    const float* e1b1  = (const float*)d_in[4];
    const float* e1w2  = (const float*)d_in[5];
    const float* e1b2  = (const float*)d_in[6];
    const float* root1 = (const float*)d_in[7];
    const float* bias1 = (const float*)d_in[8];
    const float* e2w1  = (const float*)d_in[9];
    const float* e2b1  = (const float*)d_in[10];
    const float* e2w2  = (const float*)d_in[11];
    const float* e2b2  = (const float*)d_in[12];
    const float* root2 = (const float*)d_in[13];
    const float* bias2 = (const float*)d_in[14];
    const float* fcw   = (const float*)d_in[15];
    const float* fcb   = (const float*)d_in[16];

    char* ws = (char*)d_ws;
    float*  ns1  = (float*) (ws + 0);          // [N,64] f32   2,560,000 B
    float*  ns2  = (float*) (ws + 2560000);    // [N,64] f32   2,560,000 B
    float*  cnt  = (float*) (ws + 5120000);    // [N] f32         40,000 B
    int*    flag = (int*)   (ws + 5160000);    // 4 B (+pad)
    int*    srcN = (int*)   (ws + 5160064);    // [E] int32     131,072 B
    int*    dstN = (int*)   (ws + 5291136);    // [E] int32     131,072 B
    ushort* h1   = (ushort*)(ws + 5422208);    // [N,64] bf16 1,280,000 B
    float*  h2   = (float*) (ws + 6702208);    // [N,64] f32  2,560,000 B
    ushort* B1t  = (ushort*)(ws + 9262208);    // e1w2^T bf16 [384,384]
    ushort* B2t  = (ushort*)(ws + 9557120);    // e2w2^T bf16 [4096,4096] -> ends 43,111,552

    hipMemsetAsync(d_ws, 0, 5160064, stream);   // zero ns1, ns2, cnt, flag

    idx_detect<<<1, 256, 0, stream>>>(ei, flag);
    idx_norm<<<128, 256, 0, stream>>>(ei, flag, srcN, dstN);

    transpose_f2b<<<dim3(12, 12),  dim3(32, 8), 0, stream>>>(e1w2, B1t, 384);
    transpose_f2b<<<dim3(128,128), dim3(32, 8), 0, stream>>>(e2w2, B2t, 4096);
    count_k<<<128, 256, 0, stream>>>(dstN, cnt);

    // small conv1: K=384, KS=3 -> CH=2, IP=3
    gemm_msg<384, 6, 3, float><<<NEB*3, 256, 0, stream>>>(ea, srcN, dstN, e1w1, e1b1, B1t, e1b2, x, ns1);
    node_k<6, float><<<2500, 256, 0, stream>>>(ns1, cnt, x, root1, bias1, h1, nullptr, N_NODES);

    // big conv2: K=4096, KS=16 -> CH=4, IP=32 (i-major, K-chained)
    gemm_msg<4096, 64, 16, ushort><<<NEB*16, 256, 0, stream>>>(ea, srcN, dstN, e2w1, e2b1, B2t, e2b2, h1, ns2);
    node_k<64, ushort><<<2500, 256, 0, stream>>>(ns2, cnt, h1, root2, bias2, nullptr, h2, N_NODES);

    edge_out_k<<<128, 256, 0, stream>>>(h2, srcN, dstN, ea, fcw, fcb, (float*)d_out);
}

// Round 7
// 1694.340 us; speedup vs baseline: 1.3429x; 1.3429x over previous
//
#include <hip/hip_runtime.h>

#define N_NODES 10000
#define E_EDGES 32768
#define NEB (E_EDGES/64)   // 512 edge-blocks

typedef short bf16x8v __attribute__((ext_vector_type(8)));
typedef short bf16x4v __attribute__((ext_vector_type(4)));
typedef float f32x4   __attribute__((ext_vector_type(4)));

__device__ __forceinline__ float bf2f(ushort u){
    union{ uint i; float f; } v; v.i = ((uint)u) << 16; return v.f;
}
__device__ __forceinline__ ushort f2bf(float f){
    union{ float f; uint i; } v; v.f = f;
    uint u = v.i;
    return (ushort)((u + 0x7fffu + ((u >> 16) & 1u)) >> 16);
}
__device__ __forceinline__ float ldf(float v){ return v; }
__device__ __forceinline__ float ldf(ushort v){ return bf2f(v); }

// async 16B global -> LDS (wave-uniform LDS base + lane*16)
__device__ __forceinline__ void async_copy16(const void* g, void* l){
    __builtin_amdgcn_global_load_lds(
        (const __attribute__((address_space(1))) void*)g,
        (__attribute__((address_space(3))) void*)l, 16, 0, 0);
}
// wait vmcnt(0) only (expcnt=7, lgkmcnt=15 -> no wait): gfx9 encoding
__device__ __forceinline__ void wait_vm0(){ __builtin_amdgcn_s_waitcnt(0x0F70); }

// ---------------------------------------------------------------------------
// edge_index normalization: detect int32 vs int64 layout, clamp, write int32.
// ---------------------------------------------------------------------------
__global__ void idx_detect(const int* __restrict__ w, int* __restrict__ flag){
    __shared__ int sh[256];
    int t = threadIdx.x;
    int o = 0;
    for (int i = 2*t + 1; i < 2*E_EDGES; i += 512) o |= w[i];
    sh[t] = o; __syncthreads();
    for (int s = 128; s; s >>= 1){ if (t < s) sh[t] |= sh[t+s]; __syncthreads(); }
    if (t == 0) *flag = sh[0];
}

__global__ void idx_norm(const int* __restrict__ w, const int* __restrict__ flag,
                         int* __restrict__ srcN, int* __restrict__ dstN){
    int e = blockIdx.x*256 + threadIdx.x;
    if (e >= E_EDGES) return;
    int s, d;
    if (*flag){ s = w[e];     d = w[E_EDGES + e]; }          // int32 layout
    else      { s = w[2*e];   d = w[2*E_EDGES + 2*e]; }      // int64 layout (low words)
    s = min(max(s, 0), N_NODES-1);
    d = min(max(d, 0), N_NODES-1);
    srcN[e] = s; dstN[e] = d;
}

// ---------------------------------------------------------------------------
// Fused per-edge-MLP GEMM + einsum + scatter-add. BARRIER-FREE inner loop:
//  - A fragments fully hoisted to registers (read once from LDS in prologue)
//  - B staged per-wave into wave-private 4KB double buffers via global_load_lds;
//    each wave consumes only what it staged -> no __syncthreads in the K-loop,
//    only the wave's own vmcnt drain (forced via wait_vm0 before ds_reads).
//  - i-major, K-chained through the MFMA C operand; h-scale epilogue per i-pair.
// LDS pool (32 KB) holds As chunks during prologue, then B buffers, then the
// final msg-reduction scratch.
// ---------------------------------------------------------------------------
template<int K, int NI, int KS, typename TH>
__global__ __launch_bounds__(256, 2)
void gemm_msg(const float* __restrict__ ea4,
              const int* __restrict__ srcI, const int* __restrict__ dstI,
              const float* __restrict__ w1, const float* __restrict__ b1,
              const ushort* __restrict__ Bt, const float* __restrict__ b2,
              const TH* __restrict__ hsrc,
              float* __restrict__ nodesum)
{
    constexpr int CH = K / 64 / KS;   // K-chunks per block (A resident in regs)
    constexpr int IP = NI / 2;        // i-pair passes (Ntile = 128)
    constexpr int NT = IP * CH;       // total tiles

    __shared__ __align__(16) ushort pool[16384];    // 32 KB: As / B-bufs / mr
    __shared__ __align__(16) ushort h_s[NI][68];
    __shared__ float ea_s[256];
    __shared__ int src_s[64];
    __shared__ int dst_s[64];

    const int bid  = blockIdx.x;
    const int eb   = bid % NEB;
    const int kz   = bid / NEB;
    const int t    = threadIdx.x;
    const int e0   = eb * 64;
    const int lane = t & 63;
    const int wv   = t >> 6;
    const int ng   = wv & 1;
    const int kg   = wv >> 1;
    const int q    = lane >> 4;
    const int ln   = lane & 15;

    if (t < 64){ src_s[t] = srcI[e0 + t]; dst_s[t] = dstI[e0 + t]; }
    ea_s[t] = ea4[e0 * 4 + t];
    __syncthreads();

    // stage h_s[i][row]
    if (NI == 64){
        int r = t >> 2, ig = t & 3;
        const ushort* hp = (const ushort*)hsrc + (size_t)src_s[r] * 64 + ig * 16;
        uint4 v0 = *(const uint4*)(hp);
        uint4 v1 = *(const uint4*)(hp + 8);
        const ushort* p0 = (const ushort*)&v0;
        const ushort* p1 = (const ushort*)&v1;
        #pragma unroll
        for (int ii = 0; ii < 8; ii++) h_s[ig*16 + ii    ][r] = p0[ii];
        #pragma unroll
        for (int ii = 0; ii < 8; ii++) h_s[ig*16 + 8 + ii][r] = p1[ii];
    } else {
        if (t < 64){
            const TH* hp = hsrc + (size_t)src_s[t] * NI;
            #pragma unroll
            for (int ii = 0; ii < NI; ii++) h_s[ii][t] = f2bf(ldf(hp[ii]));
        }
    }

    // stage all CH A-chunks into pool (on-the-fly edge MLP layer 1), swizzled
    #pragma unroll 1
    for (int kc = 0; kc < CH; kc++){
        int kcg = kz * CH + kc;
        #pragma unroll
        for (int s2 = 0; s2 < 2; s2++){
            int a = t + s2 * 256;
            int r = a >> 3, oct = a & 7;
            int k = kcg * 64 + oct * 8;
            float acc8[8];
            float4 b0 = *(const float4*)(b1 + k);
            float4 b4 = *(const float4*)(b1 + k + 4);
            acc8[0]=b0.x; acc8[1]=b0.y; acc8[2]=b0.z; acc8[3]=b0.w;
            acc8[4]=b4.x; acc8[5]=b4.y; acc8[6]=b4.z; acc8[7]=b4.w;
            #pragma unroll
            for (int a4 = 0; a4 < 4; a4++){
                float4 w0 = *(const float4*)(w1 + (size_t)a4 * K + k);
                float4 w4 = *(const float4*)(w1 + (size_t)a4 * K + k + 4);
                float m = ea_s[r * 4 + a4];
                acc8[0] += m * w0.x; acc8[1] += m * w0.y;
                acc8[2] += m * w0.z; acc8[3] += m * w0.w;
                acc8[4] += m * w4.x; acc8[5] += m * w4.y;
                acc8[6] += m * w4.z; acc8[7] += m * w4.w;
            }
            uint4 ov;
            ushort* po = (ushort*)&ov;
            #pragma unroll
            for (int j = 0; j < 8; j++) po[j] = f2bf(fmaxf(acc8[j], 0.f));
            *(uint4*)&pool[kc * 4096 + r * 64 + ((oct ^ (r & 7)) * 8)] = ov;
        }
    }
    __syncthreads();

    // hoist ALL A fragments to registers: afA[kc][ms]
    const int j0 = kg * 4 + q;
    bf16x8v afA[CH][4];
    #pragma unroll
    for (int kc = 0; kc < CH; kc++)
        #pragma unroll
        for (int ms = 0; ms < 4; ms++){
            int r = ms * 16 + ln;
            afA[kc][ms] = *(const bf16x8v*)&pool[kc * 4096 + r * 64 + ((j0 ^ (r & 7)) * 8)];
        }
    __syncthreads();   // pool is now free -> becomes wave-private B buffers

    // wave-private B buffer: pool[(wv*2+buf)*2048 .. +2048) ushorts (4 KB)
    // DMA permutation: lane l fetches (row = j*16 + (l>>2), oct = (l&3)^((l>>4)&3))
    // -> reader slot for (row r, oct q) is r*4 + (q^((r>>2)&3))  [2-way, free]
    const int rl4 = lane >> 2;
    const int ocp = (lane & 3) ^ ((lane >> 4) & 3);
    auto asyncB = [&](int ip, int kc, int buf){
        int kcg = kz * CH + kc;
        const ushort* gbase = Bt + (size_t)(ip * 128 + ng * 64) * K + kcg * 64 + kg * 32 + ocp * 8;
        ushort* lbase = &pool[(wv * 2 + buf) * 2048];
        #pragma unroll
        for (int j = 0; j < 4; j++)
            async_copy16(gbase + (size_t)(j * 16 + rl4) * K, lbase + j * 512);
    };

    asyncB(0, 0, 0);

    f32x4 msg[4][4];
    #pragma unroll
    for (int a = 0; a < 4; a++)
        #pragma unroll
        for (int b = 0; b < 4; b++){ msg[a][b][0]=0.f; msg[a][b][1]=0.f; msg[a][b][2]=0.f; msg[a][b][3]=0.f; }

    const f32x4 fzero = {0.f, 0.f, 0.f, 0.f};
    const int bslot = (ln * 4 + (q ^ ((ln >> 2) & 3))) * 8;   // ushort offset of this lane's b128
    int g = 0;
    #pragma unroll 1
    for (int ip = 0; ip < IP; ip++){
        f32x4 acc[4][4];
        #pragma unroll
        for (int kc = 0; kc < CH; kc++, g++){
            int buf = g & 1;
            const ushort* bwc = &pool[(wv * 2 + buf) * 2048];

            wait_vm0();   // drain this wave's DMA for buf (issued last iter)
            bf16x8v bfr[4];
            #pragma unroll
            for (int ns = 0; ns < 4; ns++)
                bfr[ns] = *(const bf16x8v*)&bwc[ns * 512 + bslot];

            // prefetch next tile into the other buffer (flies during MFMAs)
            if (g + 1 < NT){
                int nkc = (kc + 1 < CH) ? kc + 1 : 0;
                int nip = (kc + 1 < CH) ? ip : ip + 1;
                asyncB(nip, nkc, buf ^ 1);
            }

            #pragma unroll
            for (int ms = 0; ms < 4; ms++)
                #pragma unroll
                for (int ns = 0; ns < 4; ns++)
                    acc[ms][ns] = __builtin_amdgcn_mfma_f32_16x16x32_bf16(
                        afA[kc][ms], bfr[ns], (kc == 0) ? fzero : acc[ms][ns], 0, 0, 0);
        }
        // h-scale epilogue, once per i-pair (amortized over CH*16 MFMA)
        int i2 = ip * 2 + ng;
        #pragma unroll
        for (int ms = 0; ms < 4; ms++){
            bf16x4v hb = *(const bf16x4v*)&h_s[i2][ms * 16 + q * 4];
            float hf[4];
            #pragma unroll
            for (int j = 0; j < 4; j++) hf[j] = bf2f((ushort)hb[j]);
            #pragma unroll
            for (int ns = 0; ns < 4; ns++)
                #pragma unroll
                for (int j = 0; j < 4; j++)
                    msg[ms][ns][j] += hf[j] * acc[ms][ns][j];
        }
    }

    // reduce the 4 waves' msg partials in LDS (reuse pool), add b2 (kz==0), scatter
    __syncthreads();
    float* mr = (float*)&pool[0];   // [64][65] f32 = 16.6 KB
    #pragma unroll 1
    for (int r4 = 0; r4 < 4; r4++){
        if (wv == r4){
            #pragma unroll
            for (int ms = 0; ms < 4; ms++)
                #pragma unroll
                for (int ns = 0; ns < 4; ns++)
                    #pragma unroll
                    for (int j = 0; j < 4; j++){
                        int row = ms * 16 + q * 4 + j, col = ns * 16 + ln;
                        if (r4 == 0) mr[row * 65 + col]  = msg[ms][ns][j];
                        else         mr[row * 65 + col] += msg[ms][ns][j];
                    }
        }
        __syncthreads();
    }
    #pragma unroll 1
    for (int s2 = 0; s2 < 16; s2++){
        int a = t + s2 * 256;
        int row = a >> 6, o = a & 63;
        float v = mr[row * 65 + o];
        if (kz == 0){
            #pragma unroll 1
            for (int ii = 0; ii < NI; ii++)
                v += bf2f(h_s[ii][row]) * b2[ii * 64 + o];
        }
        atomicAdd(nodesum + (size_t)dst_s[row] * 64 + o, v);
    }
}

// ---------------------------------------------------------------------------
__global__ void transpose_f2b(const float* __restrict__ in, ushort* __restrict__ out, int D){
    __shared__ float tl[32][33];
    int bx = blockIdx.x, by = blockIdx.y;
    int tx = threadIdx.x, ty = threadIdx.y;
    #pragma unroll
    for (int r = 0; r < 4; r++)
        tl[ty + 8*r][tx] = in[(size_t)(by*32 + ty + 8*r) * D + bx*32 + tx];
    __syncthreads();
    #pragma unroll
    for (int r = 0; r < 4; r++)
        out[(size_t)(bx*32 + ty + 8*r) * D + by*32 + tx] = f2bf(tl[tx][ty + 8*r]);
}

__global__ void count_k(const int* __restrict__ dstI, float* __restrict__ cnt){
    int e = blockIdx.x * 256 + threadIdx.x;
    if (e < E_EDGES) atomicAdd(cnt + dstI[e], 1.f);
}

template<int NIn, typename TI>
__global__ void node_k(const float* __restrict__ ns_, const float* __restrict__ cnt,
                       const TI* __restrict__ xin, const float* __restrict__ root,
                       const float* __restrict__ bias,
                       ushort* __restrict__ hb, float* __restrict__ hf, int Nn)
{
    int idx = blockIdx.x * 256 + threadIdx.x;
    if (idx >= Nn * 64) return;
    int n = idx >> 6, o = idx & 63;
    float c = cnt[n];
    float inv = c > 1.f ? 1.f / c : 1.f;
    float s = ns_[idx] * inv + bias[o];
    #pragma unroll
    for (int i = 0; i < NIn; i++)
        s += ldf(xin[(size_t)n * NIn + i]) * root[i * 64 + o];
    s = fmaxf(s, 0.f);
    if (hb) hb[idx] = f2bf(s);
    else    hf[idx] = s;
}

// outputs FLOAT32: [E] prob | [E,3] types | [E] src | [E] dst
__global__ void edge_out_k(const float* __restrict__ h2, const int* __restrict__ srcI,
                           const int* __restrict__ dstI, const float* __restrict__ ea,
                           const float* __restrict__ fcw, const float* __restrict__ fcb,
                           float* __restrict__ out)
{
    __shared__ float fw[396];
    __shared__ float fb[3];
    int t = threadIdx.x;
    for (int i = t; i < 396; i += 256) fw[i] = fcw[i];
    if (t < 3) fb[t] = fcb[t];
    __syncthreads();
    int e = blockIdx.x * 256 + t;
    int s = srcI[e], d = dstI[e];
    const float* hs = h2 + (size_t)s * 64;
    const float* hd = h2 + (size_t)d * 64;
    float dot = 0.f, l0 = fb[0], l1 = fb[1], l2 = fb[2];
    #pragma unroll 8
    for (int c = 0; c < 64; c++){
        float a = hs[c], b = hd[c];
        dot += a * b;
        l0 += a * fw[c*3+0] + b * fw[(64+c)*3+0];
        l1 += a * fw[c*3+1] + b * fw[(64+c)*3+1];
        l2 += a * fw[c*3+2] + b * fw[(64+c)*3+2];
    }
    #pragma unroll
    for (int a4 = 0; a4 < 4; a4++){
        float v = ea[e*4 + a4];
        l0 += v * fw[(128+a4)*3+0];
        l1 += v * fw[(128+a4)*3+1];
        l2 += v * fw[(128+a4)*3+2];
    }
    float prob = 1.f / (1.f + __expf(-dot));
    float m  = fmaxf(l0, fmaxf(l1, l2));
    float x0 = __expf(l0 - m), x1 = __expf(l1 - m), x2 = __expf(l2 - m);
    float inv = 1.f / (x0 + x1 + x2);
    out[e]                  = prob;
    out[E_EDGES + 3*e + 0]  = x0 * inv;
    out[E_EDGES + 3*e + 1]  = x1 * inv;
    out[E_EDGES + 3*e + 2]  = x2 * inv;
    out[4*E_EDGES + e]      = (float)s;
    out[5*E_EDGES + e]      = (float)d;
}

// ---------------------------------------------------------------------------
extern "C" void kernel_launch(void* const* d_in, const int* in_sizes, int n_in,
                              void* d_out, int out_size, void* d_ws, size_t ws_size,
                              hipStream_t stream)
{
    const float* x     = (const float*)d_in[0];
    const int*   ei    = (const int*)  d_in[1];
    const float* ea    = (const float*)d_in[2];
    const float* e1w1  = (const float*)d_in[3];
    const float* e1b1  = (const float*)d_in[4];
    const float* e1w2  = (const float*)d_in[5];
    const float* e1b2  = (const float*)d_in[6];
    const float* root1 = (const float*)d_in[7];
    const float* bias1 = (const float*)d_in[8];
    const float* e2w1  = (const float*)d_in[9];
    const float* e2b1  = (const float*)d_in[10];
    const float* e2w2  = (const float*)d_in[11];
    const float* e2b2  = (const float*)d_in[12];
    const float* root2 = (const float*)d_in[13];
    const float* bias2 = (const float*)d_in[14];
    const float* fcw   = (const float*)d_in[15];
    const float* fcb   = (const float*)d_in[16];

    char* ws = (char*)d_ws;
    float*  ns1  = (float*) (ws + 0);          // [N,64] f32   2,560,000 B
    float*  ns2  = (float*) (ws + 2560000);    // [N,64] f32   2,560,000 B
    float*  cnt  = (float*) (ws + 5120000);    // [N] f32         40,000 B
    int*    flag = (int*)   (ws + 5160000);    // 4 B (+pad)
    int*    srcN = (int*)   (ws + 5160064);    // [E] int32     131,072 B
    int*    dstN = (int*)   (ws + 5291136);    // [E] int32     131,072 B
    ushort* h1   = (ushort*)(ws + 5422208);    // [N,64] bf16 1,280,000 B
    float*  h2   = (float*) (ws + 6702208);    // [N,64] f32  2,560,000 B
    ushort* B1t  = (ushort*)(ws + 9262208);    // e1w2^T bf16 [384,384]
    ushort* B2t  = (ushort*)(ws + 9557120);    // e2w2^T bf16 [4096,4096] -> ends 43,111,552

    hipMemsetAsync(d_ws, 0, 5160064, stream);   // zero ns1, ns2, cnt, flag

    idx_detect<<<1, 256, 0, stream>>>(ei, flag);
    idx_norm<<<128, 256, 0, stream>>>(ei, flag, srcN, dstN);

    transpose_f2b<<<dim3(12, 12),  dim3(32, 8), 0, stream>>>(e1w2, B1t, 384);
    transpose_f2b<<<dim3(128,128), dim3(32, 8), 0, stream>>>(e2w2, B2t, 4096);
    count_k<<<128, 256, 0, stream>>>(dstN, cnt);

    // small conv1: K=384, KS=3 -> CH=2, IP=3
    gemm_msg<384, 6, 3, float><<<NEB*3, 256, 0, stream>>>(ea, srcN, dstN, e1w1, e1b1, B1t, e1b2, x, ns1);
    node_k<6, float><<<2500, 256, 0, stream>>>(ns1, cnt, x, root1, bias1, h1, nullptr, N_NODES);

    // big conv2: K=4096, KS=16 -> CH=4, IP=32 (i-major, K-chained, barrier-free)
    gemm_msg<4096, 64, 16, ushort><<<NEB*16, 256, 0, stream>>>(ea, srcN, dstN, e2w1, e2b1, B2t, e2b2, h1, ns2);
    node_k<64, ushort><<<2500, 256, 0, stream>>>(ns2, cnt, h1, root2, bias2, nullptr, h2, N_NODES);

    edge_out_k<<<128, 256, 0, stream>>>(h2, srcN, dstN, ea, fcw, fcb, (float*)d_out);
}

// Round 8
// 1667.848 us; speedup vs baseline: 1.3642x; 1.0159x over previous
//
#include <hip/hip_runtime.h>

#define N_NODES 10000
#define E_EDGES 32768
#define NEB (E_EDGES/64)   // 512 edge-blocks

typedef short bf16x8v __attribute__((ext_vector_type(8)));
typedef short bf16x4v __attribute__((ext_vector_type(4)));
typedef float f32x4   __attribute__((ext_vector_type(4)));

__device__ __forceinline__ float bf2f(ushort u){
    union{ uint i; float f; } v; v.i = ((uint)u) << 16; return v.f;
}
__device__ __forceinline__ ushort f2bf(float f){
    union{ float f; uint i; } v; v.f = f;
    uint u = v.i;
    return (ushort)((u + 0x7fffu + ((u >> 16) & 1u)) >> 16);
}
__device__ __forceinline__ float ldf(float v){ return v; }
__device__ __forceinline__ float ldf(ushort v){ return bf2f(v); }

// async 16B global -> LDS (wave-uniform LDS base + lane*16)
__device__ __forceinline__ void async_copy16(const void* g, void* l){
    __builtin_amdgcn_global_load_lds(
        (const __attribute__((address_space(1))) void*)g,
        (__attribute__((address_space(3))) void*)l, 16, 0, 0);
}
// gfx9 s_waitcnt imm: vmcnt[3:0]=bits3:0, expcnt=bits6:4, lgkmcnt=bits11:8, vmcnt[5:4]=bits15:14
__device__ __forceinline__ void wait_vm0(){ __builtin_amdgcn_s_waitcnt(0x0F70); }  // vmcnt(0)
__device__ __forceinline__ void wait_vm4(){ __builtin_amdgcn_s_waitcnt(0x0F74); }  // vmcnt(4)

// ---------------------------------------------------------------------------
// edge_index normalization: detect int32 vs int64 layout, clamp, write int32.
// ---------------------------------------------------------------------------
__global__ void idx_detect(const int* __restrict__ w, int* __restrict__ flag){
    __shared__ int sh[256];
    int t = threadIdx.x;
    int o = 0;
    for (int i = 2*t + 1; i < 2*E_EDGES; i += 512) o |= w[i];
    sh[t] = o; __syncthreads();
    for (int s = 128; s; s >>= 1){ if (t < s) sh[t] |= sh[t+s]; __syncthreads(); }
    if (t == 0) *flag = sh[0];
}

__global__ void idx_norm(const int* __restrict__ w, const int* __restrict__ flag,
                         int* __restrict__ srcN, int* __restrict__ dstN){
    int e = blockIdx.x*256 + threadIdx.x;
    if (e >= E_EDGES) return;
    int s, d;
    if (*flag){ s = w[e];     d = w[E_EDGES + e]; }          // int32 layout
    else      { s = w[2*e];   d = w[2*E_EDGES + 2*e]; }      // int64 layout (low words)
    s = min(max(s, 0), N_NODES-1);
    d = min(max(d, 0), N_NODES-1);
    srcN[e] = s; dstN[e] = d;
}

// ---------------------------------------------------------------------------
// Fused per-edge-MLP GEMM + einsum + scatter-add. Barrier-free K-loop with
// DEPTH-2 wave-private prefetch (triple buffer, wait vmcnt(4) never 0 except
// the final tile — AITER-style). A fragments fully hoisted to registers.
// i-major, K-chained through the MFMA C operand; h-scale epilogue per i-pair.
// ---------------------------------------------------------------------------
template<int K, int NI, int KS, typename TH>
__global__ __launch_bounds__(256, 2)
void gemm_msg(const float* __restrict__ ea4,
              const int* __restrict__ srcI, const int* __restrict__ dstI,
              const float* __restrict__ w1, const float* __restrict__ b1,
              const ushort* __restrict__ Bt, const float* __restrict__ b2,
              const TH* __restrict__ hsrc,
              float* __restrict__ nodesum)
{
    constexpr int CH = K / 64 / KS;   // K-chunks per block (A resident in regs)
    constexpr int IP = NI / 2;        // i-pair passes (Ntile = 128)
    constexpr int NT = IP * CH;       // total tiles (>= 2)

    __shared__ __align__(16) ushort pool[24576];    // 48 KB: As / B-bufs / mr
    __shared__ __align__(16) ushort h_s[NI][68];
    __shared__ float ea_s[256];
    __shared__ int src_s[64];
    __shared__ int dst_s[64];

    const int bid  = blockIdx.x;
    const int eb   = bid % NEB;
    const int kz   = bid / NEB;
    const int t    = threadIdx.x;
    const int e0   = eb * 64;
    const int lane = t & 63;
    const int wv   = t >> 6;
    const int ng   = wv & 1;
    const int kg   = wv >> 1;
    const int q    = lane >> 4;
    const int ln   = lane & 15;

    if (t < 64){ src_s[t] = srcI[e0 + t]; dst_s[t] = dstI[e0 + t]; }
    ea_s[t] = ea4[e0 * 4 + t];
    __syncthreads();

    // stage h_s[i][row]
    if (NI == 64){
        int r = t >> 2, ig = t & 3;
        const ushort* hp = (const ushort*)hsrc + (size_t)src_s[r] * 64 + ig * 16;
        uint4 v0 = *(const uint4*)(hp);
        uint4 v1 = *(const uint4*)(hp + 8);
        const ushort* p0 = (const ushort*)&v0;
        const ushort* p1 = (const ushort*)&v1;
        #pragma unroll
        for (int ii = 0; ii < 8; ii++) h_s[ig*16 + ii    ][r] = p0[ii];
        #pragma unroll
        for (int ii = 0; ii < 8; ii++) h_s[ig*16 + 8 + ii][r] = p1[ii];
    } else {
        if (t < 64){
            const TH* hp = hsrc + (size_t)src_s[t] * NI;
            #pragma unroll
            for (int ii = 0; ii < NI; ii++) h_s[ii][t] = f2bf(ldf(hp[ii]));
        }
    }

    // stage all CH A-chunks into pool (on-the-fly edge MLP layer 1), swizzled
    #pragma unroll 1
    for (int kc = 0; kc < CH; kc++){
        int kcg = kz * CH + kc;
        #pragma unroll
        for (int s2 = 0; s2 < 2; s2++){
            int a = t + s2 * 256;
            int r = a >> 3, oct = a & 7;
            int k = kcg * 64 + oct * 8;
            float acc8[8];
            float4 b0 = *(const float4*)(b1 + k);
            float4 b4 = *(const float4*)(b1 + k + 4);
            acc8[0]=b0.x; acc8[1]=b0.y; acc8[2]=b0.z; acc8[3]=b0.w;
            acc8[4]=b4.x; acc8[5]=b4.y; acc8[6]=b4.z; acc8[7]=b4.w;
            #pragma unroll
            for (int a4 = 0; a4 < 4; a4++){
                float4 w0 = *(const float4*)(w1 + (size_t)a4 * K + k);
                float4 w4 = *(const float4*)(w1 + (size_t)a4 * K + k + 4);
                float m = ea_s[r * 4 + a4];
                acc8[0] += m * w0.x; acc8[1] += m * w0.y;
                acc8[2] += m * w0.z; acc8[3] += m * w0.w;
                acc8[4] += m * w4.x; acc8[5] += m * w4.y;
                acc8[6] += m * w4.z; acc8[7] += m * w4.w;
            }
            uint4 ov;
            ushort* po = (ushort*)&ov;
            #pragma unroll
            for (int j = 0; j < 8; j++) po[j] = f2bf(fmaxf(acc8[j], 0.f));
            *(uint4*)&pool[kc * 4096 + r * 64 + ((oct ^ (r & 7)) * 8)] = ov;
        }
    }
    __syncthreads();

    // hoist ALL A fragments to registers: afA[kc][ms]
    const int j0 = kg * 4 + q;
    bf16x8v afA[CH][4];
    #pragma unroll
    for (int kc = 0; kc < CH; kc++)
        #pragma unroll
        for (int ms = 0; ms < 4; ms++){
            int r = ms * 16 + ln;
            afA[kc][ms] = *(const bf16x8v*)&pool[kc * 4096 + r * 64 + ((j0 ^ (r & 7)) * 8)];
        }
    __syncthreads();   // pool is now free -> becomes wave-private B buffers

    // wave-private B buffer: pool[(wv*3+buf)*2048 .. +2048) ushorts, buf in {0,1,2}
    // DMA perm: lane l fetches (row = j*16 + (l>>2), oct = (l&3)^((l>>4)&3));
    // reader slot for (row r, oct o) = (r>>4)*64 + (r&15)*4 + (o^((r>>2)&3))
    const int rl4 = lane >> 2;
    const int ocp = (lane & 3) ^ ((lane >> 4) & 3);
    auto asyncB = [&](int ip, int kc, int buf){
        int kcg = kz * CH + kc;
        const ushort* gbase = Bt + (size_t)(ip * 128 + ng * 64) * K + kcg * 64 + kg * 32 + ocp * 8;
        ushort* lbase = &pool[(wv * 3 + buf) * 2048];
        #pragma unroll
        for (int j = 0; j < 4; j++)
            async_copy16(gbase + (size_t)(j * 16 + rl4) * K, lbase + j * 512);
    };

    // prologue: issue tiles 0 and 1 (depth-2)
    asyncB(0, 0, 0);
    {
        int nkc1 = (1 < CH) ? 1 : 0;
        int nip1 = (1 < CH) ? 0 : 1;
        asyncB(nip1, nkc1, 1);
    }

    f32x4 msg[4][4];
    #pragma unroll
    for (int a = 0; a < 4; a++)
        #pragma unroll
        for (int b = 0; b < 4; b++){ msg[a][b][0]=0.f; msg[a][b][1]=0.f; msg[a][b][2]=0.f; msg[a][b][3]=0.f; }

    const f32x4 fzero = {0.f, 0.f, 0.f, 0.f};
    const int bslot = (ln * 4 + (q ^ ((ln >> 2) & 3))) * 8;   // ushort offset of this lane's b128
    int g = 0;
    int bufc = 0;   // consume buffer
    int bufi = 2;   // issue buffer (for tile g+2)
    #pragma unroll 1
    for (int ip = 0; ip < IP; ip++){
        f32x4 acc[4][4];
        #pragma unroll
        for (int kc = 0; kc < CH; kc++, g++){
            const ushort* bwc = &pool[(wv * 3 + bufc) * 2048];

            if (g < NT - 1) wait_vm4();   // oldest tile (g) landed; g+1 stays in flight
            else            wait_vm0();   // final tile

            bf16x8v bfr[4];
            #pragma unroll
            for (int ns = 0; ns < 4; ns++)
                bfr[ns] = *(const bf16x8v*)&bwc[ns * 512 + bslot];

            // prefetch tile g+2 (flies across the next full iteration)
            if (g + 2 < NT){
                int g2 = g + 2;
                int nip = g2 / CH, nkc = g2 % CH;
                asyncB(nip, nkc, bufi);
            }

            #pragma unroll
            for (int ms = 0; ms < 4; ms++)
                #pragma unroll
                for (int ns = 0; ns < 4; ns++)
                    acc[ms][ns] = __builtin_amdgcn_mfma_f32_16x16x32_bf16(
                        afA[kc][ms], bfr[ns], (kc == 0) ? fzero : acc[ms][ns], 0, 0, 0);

            bufc = (bufc == 2) ? 0 : bufc + 1;
            bufi = (bufi == 2) ? 0 : bufi + 1;
        }
        // h-scale epilogue, once per i-pair (amortized over CH*16 MFMA)
        int i2 = ip * 2 + ng;
        #pragma unroll
        for (int ms = 0; ms < 4; ms++){
            bf16x4v hb = *(const bf16x4v*)&h_s[i2][ms * 16 + q * 4];
            float hf[4];
            #pragma unroll
            for (int j = 0; j < 4; j++) hf[j] = bf2f((ushort)hb[j]);
            #pragma unroll
            for (int ns = 0; ns < 4; ns++)
                #pragma unroll
                for (int j = 0; j < 4; j++)
                    msg[ms][ns][j] += hf[j] * acc[ms][ns][j];
        }
    }

    // reduce the 4 waves' msg partials in LDS (reuse pool), add b2 (kz==0), scatter
    __syncthreads();
    float* mr = (float*)&pool[0];   // [64][65] f32 = 16.6 KB
    #pragma unroll 1
    for (int r4 = 0; r4 < 4; r4++){
        if (wv == r4){
            #pragma unroll
            for (int ms = 0; ms < 4; ms++)
                #pragma unroll
                for (int ns = 0; ns < 4; ns++)
                    #pragma unroll
                    for (int j = 0; j < 4; j++){
                        int row = ms * 16 + q * 4 + j, col = ns * 16 + ln;
                        if (r4 == 0) mr[row * 65 + col]  = msg[ms][ns][j];
                        else         mr[row * 65 + col] += msg[ms][ns][j];
                    }
        }
        __syncthreads();
    }
    #pragma unroll 1
    for (int s2 = 0; s2 < 16; s2++){
        int a = t + s2 * 256;
        int row = a >> 6, o = a & 63;
        float v = mr[row * 65 + o];
        if (kz == 0){
            #pragma unroll 1
            for (int ii = 0; ii < NI; ii++)
                v += bf2f(h_s[ii][row]) * b2[ii * 64 + o];
        }
        atomicAdd(nodesum + (size_t)dst_s[row] * 64 + o, v);
    }
}

// ---------------------------------------------------------------------------
__global__ void transpose_f2b(const float* __restrict__ in, ushort* __restrict__ out, int D){
    __shared__ float tl[32][33];
    int bx = blockIdx.x, by = blockIdx.y;
    int tx = threadIdx.x, ty = threadIdx.y;
    #pragma unroll
    for (int r = 0; r < 4; r++)
        tl[ty + 8*r][tx] = in[(size_t)(by*32 + ty + 8*r) * D + bx*32 + tx];
    __syncthreads();
    #pragma unroll
    for (int r = 0; r < 4; r++)
        out[(size_t)(bx*32 + ty + 8*r) * D + by*32 + tx] = f2bf(tl[tx][ty + 8*r]);
}

__global__ void count_k(const int* __restrict__ dstI, float* __restrict__ cnt){
    int e = blockIdx.x * 256 + threadIdx.x;
    if (e < E_EDGES) atomicAdd(cnt + dstI[e], 1.f);
}

template<int NIn, typename TI>
__global__ void node_k(const float* __restrict__ ns_, const float* __restrict__ cnt,
                       const TI* __restrict__ xin, const float* __restrict__ root,
                       const float* __restrict__ bias,
                       ushort* __restrict__ hb, float* __restrict__ hf, int Nn)
{
    int idx = blockIdx.x * 256 + threadIdx.x;
    if (idx >= Nn * 64) return;
    int n = idx >> 6, o = idx & 63;
    float c = cnt[n];
    float inv = c > 1.f ? 1.f / c : 1.f;
    float s = ns_[idx] * inv + bias[o];
    #pragma unroll
    for (int i = 0; i < NIn; i++)
        s += ldf(xin[(size_t)n * NIn + i]) * root[i * 64 + o];
    s = fmaxf(s, 0.f);
    if (hb) hb[idx] = f2bf(s);
    else    hf[idx] = s;
}

// outputs FLOAT32: [E] prob | [E,3] types | [E] src | [E] dst
__global__ void edge_out_k(const float* __restrict__ h2, const int* __restrict__ srcI,
                           const int* __restrict__ dstI, const float* __restrict__ ea,
                           const float* __restrict__ fcw, const float* __restrict__ fcb,
                           float* __restrict__ out)
{
    __shared__ float fw[396];
    __shared__ float fb[3];
    int t = threadIdx.x;
    for (int i = t; i < 396; i += 256) fw[i] = fcw[i];
    if (t < 3) fb[t] = fcb[t];
    __syncthreads();
    int e = blockIdx.x * 256 + t;
    int s = srcI[e], d = dstI[e];
    const float* hs = h2 + (size_t)s * 64;
    const float* hd = h2 + (size_t)d * 64;
    float dot = 0.f, l0 = fb[0], l1 = fb[1], l2 = fb[2];
    #pragma unroll 8
    for (int c = 0; c < 64; c++){
        float a = hs[c], b = hd[c];
        dot += a * b;
        l0 += a * fw[c*3+0] + b * fw[(64+c)*3+0];
        l1 += a * fw[c*3+1] + b * fw[(64+c)*3+1];
        l2 += a * fw[c*3+2] + b * fw[(64+c)*3+2];
    }
    #pragma unroll
    for (int a4 = 0; a4 < 4; a4++){
        float v = ea[e*4 + a4];
        l0 += v * fw[(128+a4)*3+0];
        l1 += v * fw[(128+a4)*3+1];
        l2 += v * fw[(128+a4)*3+2];
    }
    float prob = 1.f / (1.f + __expf(-dot));
    float m  = fmaxf(l0, fmaxf(l1, l2));
    float x0 = __expf(l0 - m), x1 = __expf(l1 - m), x2 = __expf(l2 - m);
    float inv = 1.f / (x0 + x1 + x2);
    out[e]                  = prob;
    out[E_EDGES + 3*e + 0]  = x0 * inv;
    out[E_EDGES + 3*e + 1]  = x1 * inv;
    out[E_EDGES + 3*e + 2]  = x2 * inv;
    out[4*E_EDGES + e]      = (float)s;
    out[5*E_EDGES + e]      = (float)d;
}

// ---------------------------------------------------------------------------
extern "C" void kernel_launch(void* const* d_in, const int* in_sizes, int n_in,
                              void* d_out, int out_size, void* d_ws, size_t ws_size,
                              hipStream_t stream)
{
    const float* x     = (const float*)d_in[0];
    const int*   ei    = (const int*)  d_in[1];
    const float* ea    = (const float*)d_in[2];
    const float* e1w1  = (const float*)d_in[3];
    const float* e1b1  = (const float*)d_in[4];
    const float* e1w2  = (const float*)d_in[5];
    const float* e1b2  = (const float*)d_in[6];
    const float* root1 = (const float*)d_in[7];
    const float* bias1 = (const float*)d_in[8];
    const float* e2w1  = (const float*)d_in[9];
    const float* e2b1  = (const float*)d_in[10];
    const float* e2w2  = (const float*)d_in[11];
    const float* e2b2  = (const float*)d_in[12];
    const float* root2 = (const float*)d_in[13];
    const float* bias2 = (const float*)d_in[14];
    const float* fcw   = (const float*)d_in[15];
    const float* fcb   = (const float*)d_in[16];

    char* ws = (char*)d_ws;
    float*  ns1  = (float*) (ws + 0);          // [N,64] f32   2,560,000 B
    float*  ns2  = (float*) (ws + 2560000);    // [N,64] f32   2,560,000 B
    float*  cnt  = (float*) (ws + 5120000);    // [N] f32         40,000 B
    int*    flag = (int*)   (ws + 5160000);    // 4 B (+pad)
    int*    srcN = (int*)   (ws + 5160064);    // [E] int32     131,072 B
    int*    dstN = (int*)   (ws + 5291136);    // [E] int32     131,072 B
    ushort* h1   = (ushort*)(ws + 5422208);    // [N,64] bf16 1,280,000 B
    float*  h2   = (float*) (ws + 6702208);    // [N,64] f32  2,560,000 B
    ushort* B1t  = (ushort*)(ws + 9262208);    // e1w2^T bf16 [384,384]
    ushort* B2t  = (ushort*)(ws + 9557120);    // e2w2^T bf16 [4096,4096] -> ends 43,111,552

    hipMemsetAsync(d_ws, 0, 5160064, stream);   // zero ns1, ns2, cnt, flag

    idx_detect<<<1, 256, 0, stream>>>(ei, flag);
    idx_norm<<<128, 256, 0, stream>>>(ei, flag, srcN, dstN);

    transpose_f2b<<<dim3(12, 12),  dim3(32, 8), 0, stream>>>(e1w2, B1t, 384);
    transpose_f2b<<<dim3(128,128), dim3(32, 8), 0, stream>>>(e2w2, B2t, 4096);
    count_k<<<128, 256, 0, stream>>>(dstN, cnt);

    // small conv1: K=384, KS=3 -> CH=2, IP=3
    gemm_msg<384, 6, 3, float><<<NEB*3, 256, 0, stream>>>(ea, srcN, dstN, e1w1, e1b1, B1t, e1b2, x, ns1);
    node_k<6, float><<<2500, 256, 0, stream>>>(ns1, cnt, x, root1, bias1, h1, nullptr, N_NODES);

    // big conv2: K=4096, KS=16 -> CH=4, IP=32 (i-major, K-chained, depth-2 prefetch)
    gemm_msg<4096, 64, 16, ushort><<<NEB*16, 256, 0, stream>>>(ea, srcN, dstN, e2w1, e2b1, B2t, e2b2, h1, ns2);
    node_k<64, ushort><<<2500, 256, 0, stream>>>(ns2, cnt, h1, root2, bias2, nullptr, h2, N_NODES);

    edge_out_k<<<128, 256, 0, stream>>>(h2, srcN, dstN, ea, fcw, fcb, (float*)d_out);
}